// Round 1
// baseline (885.501 us; speedup 1.0000x reference)
//
#include <hip/hip_runtime.h>

#define N_ROWS 8192
#define IN_DIM 256
#define HID 128

typedef __attribute__((ext_vector_type(8))) short bf16x8;
typedef __attribute__((ext_vector_type(4))) float f32x4;

__device__ __forceinline__ unsigned short f2bf(float f) {
    union { float f; unsigned u; } v; v.f = f;
    unsigned r = (v.u + 0x7FFFu + ((v.u >> 16) & 1u)) >> 16;
    return (unsigned short)r;
}

// ---------------- pack: 4 weights [K][HO] -> WT bf16 [4*HO][K], biases -> B [4*HO]
__global__ void pack_weights(const float* __restrict__ W0, const float* __restrict__ W1,
                             const float* __restrict__ W2, const float* __restrict__ W3,
                             const float* __restrict__ b0, const float* __restrict__ b1,
                             const float* __restrict__ b2, const float* __restrict__ b3,
                             unsigned short* __restrict__ WT, float* __restrict__ B,
                             int K, int HO)
{
    int NT = 4 * HO;
    int idx = blockIdx.x * blockDim.x + threadIdx.x;
    if (idx < NT * K) {
        int n = idx / K, k = idx - n * K;
        int s = n / HO, sn = n - s * HO;
        const float* W = (s == 0) ? W0 : (s == 1) ? W1 : (s == 2) ? W2 : W3;
        WT[idx] = f2bf(W[k * HO + sn]);
    }
    if (idx < NT) {
        int s = idx / HO, sn = idx - s * HO;
        const float* b = (s == 0) ? b0 : (s == 1) ? b1 : (s == 2) ? b2 : b3;
        B[idx] = b[sn];
    }
}

__global__ void cast_x(const float* __restrict__ in, unsigned short* __restrict__ out, int n) {
    int i = blockIdx.x * blockDim.x + threadIdx.x;
    if (i < n) out[i] = f2bf(in[i]);
}

// ---------------- fused projection GEMM: A[M][K] bf16 x WT[NT][K] -> q,k,v bf16 + skip f32
// wave computes 16 rows x 64 cols. MFMA 16x16x32 bf16.
template<int K>
__global__ __launch_bounds__(256) void proj_gemm(
    const unsigned short* __restrict__ A, const unsigned short* __restrict__ WT,
    const float* __restrict__ bias,
    unsigned short* __restrict__ qo, unsigned short* __restrict__ ko,
    unsigned short* __restrict__ vo, float* __restrict__ skip,
    int NT)
{
    const int lane = threadIdx.x & 63;
    const int wid = (blockIdx.x * blockDim.x + threadIdx.x) >> 6;
    const int nStrips = NT / 64;
    const int mTile = wid / nStrips;
    const int nBase = (wid - mTile * nStrips) * 64;
    const int l15 = lane & 15, lg = lane >> 4;
    const int HO = NT >> 2;

    f32x4 acc[4];
    #pragma unroll
    for (int c = 0; c < 4; ++c) acc[c] = f32x4{0.f, 0.f, 0.f, 0.f};

    const unsigned short* Ap = A + (size_t)(mTile * 16 + l15) * K + lg * 8;
    #pragma unroll
    for (int t = 0; t < K / 32; ++t) {
        bf16x8 a = *(const bf16x8*)(Ap + t * 32);
        #pragma unroll
        for (int c = 0; c < 4; ++c) {
            bf16x8 b = *(const bf16x8*)(WT + (size_t)(nBase + c * 16 + l15) * K + t * 32 + lg * 8);
            acc[c] = __builtin_amdgcn_mfma_f32_16x16x32_bf16(a, b, acc[c], 0, 0, 0);
        }
    }
    #pragma unroll
    for (int c = 0; c < 4; ++c) {
        int col = nBase + c * 16 + l15;
        int sec = col / HO, sc = col - sec * HO;
        float bv = bias[col];
        #pragma unroll
        for (int r = 0; r < 4; ++r) {
            int mrow = mTile * 16 + lg * 4 + r;
            float val = acc[c][r] + bv;
            size_t o = (size_t)mrow * HO + sc;
            if (sec == 0) qo[o] = f2bf(val);
            else if (sec == 1) ko[o] = f2bf(val);
            else if (sec == 2) vo[o] = f2bf(val);
            else skip[o] = val;
        }
    }
}

// ---------------- flash-attention partial over a K-chunk.
// Block: 4 waves, 64 q-rows (16/wave). K staged row-major (+8 pad); V staged transposed.
template<int D, int KB>
__global__ __launch_bounds__(256) void attn_partial(
    const unsigned short* __restrict__ Qm,
    const unsigned short* __restrict__ Km,
    const unsigned short* __restrict__ Vm,
    float* __restrict__ accOut, float* __restrict__ mOut, float* __restrict__ lOut,
    int chunkLen, float scale)
{
    constexpr int LK = D + 8;
    constexpr int LV = KB + 8;
    constexpr int LP = KB + 8;
    __shared__ __align__(16) unsigned short Kl[KB * LK];
    __shared__ __align__(16) unsigned short VTl[D * LV];
    __shared__ __align__(16) unsigned short Pl[4 * 16 * LP];

    const int lane = threadIdx.x & 63;
    const int w = threadIdx.x >> 6;
    const int l15 = lane & 15, lg = lane >> 4;
    const int qrow = blockIdx.x * 64 + w * 16;
    const int ch = blockIdx.y;
    const int kStart = ch * chunkLen;
    const int NN = N_ROWS;

    bf16x8 qf[D / 32];
    #pragma unroll
    for (int t = 0; t < D / 32; ++t)
        qf[t] = *(const bf16x8*)(Qm + (size_t)(qrow + l15) * D + t * 32 + lg * 8);

    f32x4 acc[D / 16];
    #pragma unroll
    for (int dt = 0; dt < D / 16; ++dt) acc[dt] = f32x4{0.f, 0.f, 0.f, 0.f};
    float mRow[4] = {-__builtin_inff(), -__builtin_inff(), -__builtin_inff(), -__builtin_inff()};
    float lRow[4] = {0.f, 0.f, 0.f, 0.f};

    for (int kt = 0; kt < chunkLen; kt += KB) {
        __syncthreads();
        const int kGlob = kStart + kt;
        for (int c = threadIdx.x; c < KB * D / 8; c += 256) {
            int r = c / (D / 8), c8 = c - r * (D / 8);
            int4 kv = *(const int4*)(Km + (size_t)(kGlob + r) * D + c8 * 8);
            *(int4*)(&Kl[r * LK + c8 * 8]) = kv;
            int4 vv = *(const int4*)(Vm + (size_t)(kGlob + r) * D + c8 * 8);
            const unsigned short* ve = (const unsigned short*)&vv;
            #pragma unroll
            for (int i = 0; i < 8; ++i)
                VTl[(c8 * 8 + i) * LV + r] = ve[i];
        }
        __syncthreads();

        // S = Q @ K^T  (rows q, cols k)
        f32x4 s[KB / 16];
        #pragma unroll
        for (int c = 0; c < KB / 16; ++c) {
            s[c] = f32x4{0.f, 0.f, 0.f, 0.f};
            #pragma unroll
            for (int t = 0; t < D / 32; ++t) {
                bf16x8 b = *(const bf16x8*)(&Kl[(c * 16 + l15) * LK + t * 32 + lg * 8]);
                s[c] = __builtin_amdgcn_mfma_f32_16x16x32_bf16(qf[t], b, s[c], 0, 0, 0);
            }
        }
        // scale + row max (rows live across 16 lanes of each group)
        float tmax[4];
        #pragma unroll
        for (int r = 0; r < 4; ++r) {
            float v = -__builtin_inff();
            #pragma unroll
            for (int c = 0; c < KB / 16; ++c) { s[c][r] *= scale; v = fmaxf(v, s[c][r]); }
            #pragma unroll
            for (int mk = 1; mk <= 8; mk <<= 1) v = fmaxf(v, __shfl_xor(v, mk));
            tmax[r] = v;
        }
        float alpha[4];
        #pragma unroll
        for (int r = 0; r < 4; ++r) {
            float mNew = fmaxf(mRow[r], tmax[r]);
            alpha[r] = __expf(mRow[r] - mNew);
            mRow[r] = mNew;
        }
        // P = exp(S - m), write per-wave LDS region, accumulate row sums
        float ls[4] = {0.f, 0.f, 0.f, 0.f};
        #pragma unroll
        for (int c = 0; c < KB / 16; ++c) {
            #pragma unroll
            for (int r = 0; r < 4; ++r) {
                float p = __expf(s[c][r] - mRow[r]);
                ls[r] += p;
                Pl[(w * 16 + lg * 4 + r) * LP + c * 16 + l15] = f2bf(p);
            }
        }
        #pragma unroll
        for (int r = 0; r < 4; ++r) {
            float v = ls[r];
            #pragma unroll
            for (int mk = 1; mk <= 8; mk <<= 1) v += __shfl_xor(v, mk);
            lRow[r] = lRow[r] * alpha[r] + v;
        }
        #pragma unroll
        for (int dt = 0; dt < D / 16; ++dt) {
            #pragma unroll
            for (int r = 0; r < 4; ++r) acc[dt][r] *= alpha[r];
        }
        // PV: out += P @ V   (A = P rows q, B = V via VT rows d)
        #pragma unroll
        for (int dt = 0; dt < D / 16; ++dt) {
            #pragma unroll
            for (int ks = 0; ks < KB / 32; ++ks) {
                bf16x8 a = *(const bf16x8*)(&Pl[(w * 16 + l15) * LP + ks * 32 + lg * 8]);
                bf16x8 b = *(const bf16x8*)(&VTl[(dt * 16 + l15) * LV + ks * 32 + lg * 8]);
                acc[dt] = __builtin_amdgcn_mfma_f32_16x16x32_bf16(a, b, acc[dt], 0, 0, 0);
            }
        }
    }

    #pragma unroll
    for (int dt = 0; dt < D / 16; ++dt) {
        #pragma unroll
        for (int r = 0; r < 4; ++r)
            accOut[((size_t)ch * NN + qrow + lg * 4 + r) * D + dt * 16 + l15] = acc[dt][r];
    }
    if (l15 == 0) {
        #pragma unroll
        for (int r = 0; r < 4; ++r) {
            mOut[ch * NN + qrow + lg * 4 + r] = mRow[r];
            lOut[ch * NN + qrow + lg * 4 + r] = lRow[r];
        }
    }
}

// ---------------- combine K-split partials + skip (+ optional ELU -> bf16)
template<int D, bool ELU>
__global__ void combine_kernel(const float* __restrict__ acc, const float* __restrict__ mArr,
                               const float* __restrict__ lArr, const float* __restrict__ skip,
                               float* __restrict__ outF, unsigned short* __restrict__ outB,
                               int CH)
{
    const int row = blockIdx.x;
    const int d = threadIdx.x;
    const size_t NN = N_ROWS;
    float mStar = -__builtin_inff();
    for (int c = 0; c < CH; ++c) mStar = fmaxf(mStar, mArr[c * NN + row]);
    float denom = 0.f, val = 0.f;
    for (int c = 0; c < CH; ++c) {
        float wgt = __expf(mArr[c * NN + row] - mStar);
        denom += wgt * lArr[c * NN + row];
        val += wgt * acc[((size_t)c * NN + row) * D + d];
    }
    float v = val / denom + skip[(size_t)row * D + d];
    if (ELU) {
        v = (v > 0.f) ? v : expm1f(v);
        outB[(size_t)row * D + d] = f2bf(v);
    } else {
        outF[(size_t)row * D + d] = v;
    }
}

extern "C" void kernel_launch(void* const* d_in, const int* in_sizes, int n_in,
                              void* d_out, int out_size, void* d_ws, size_t ws_size,
                              hipStream_t stream)
{
    (void)in_sizes; (void)n_in; (void)out_size;
    const float* x   = (const float*)d_in[0];
    // d_in[1]=XY_Adj, d_in[2]=w0, d_in[3]=w1 : unused (sim matrix is dead in reference)
    const float* Wq1 = (const float*)d_in[4];
    const float* bq1 = (const float*)d_in[5];
    const float* Wk1 = (const float*)d_in[6];
    const float* bk1 = (const float*)d_in[7];
    const float* Wv1 = (const float*)d_in[8];
    const float* bv1 = (const float*)d_in[9];
    const float* Ws1 = (const float*)d_in[10];
    const float* bs1 = (const float*)d_in[11];
    const float* Wq4 = (const float*)d_in[12];
    const float* bq4 = (const float*)d_in[13];
    const float* Wk4 = (const float*)d_in[14];
    const float* bk4 = (const float*)d_in[15];
    const float* Wv4 = (const float*)d_in[16];
    const float* bv4 = (const float*)d_in[17];
    const float* Ws4 = (const float*)d_in[18];
    const float* bs4 = (const float*)d_in[19];
    float* out = (float*)d_out;

    const int N = N_ROWS;
    size_t off = 0;
    auto alloc = [&](size_t bytes) -> void* {
        void* p = (char*)d_ws + off;
        off = (off + bytes + 255) & ~(size_t)255;
        return p;
    };
    unsigned short* xb  = (unsigned short*)alloc((size_t)N * IN_DIM * 2);
    unsigned short* WT1 = (unsigned short*)alloc((size_t)512 * 256 * 2);
    float* B1           = (float*)alloc(512 * 4);
    unsigned short* WT4 = (unsigned short*)alloc((size_t)1024 * 128 * 2);
    float* B4           = (float*)alloc(1024 * 4);
    unsigned short* q1  = (unsigned short*)alloc((size_t)N * HID * 2);
    unsigned short* k1  = (unsigned short*)alloc((size_t)N * HID * 2);
    unsigned short* v1  = (unsigned short*)alloc((size_t)N * HID * 2);
    float* skip1        = (float*)alloc((size_t)N * HID * 4);
    unsigned short* h1  = (unsigned short*)alloc((size_t)N * HID * 2);
    unsigned short* q4  = (unsigned short*)alloc((size_t)N * IN_DIM * 2);
    unsigned short* k4  = (unsigned short*)alloc((size_t)N * IN_DIM * 2);
    unsigned short* v4  = (unsigned short*)alloc((size_t)N * IN_DIM * 2);
    float* skip4        = (float*)alloc((size_t)N * IN_DIM * 4);

    size_t fixedEnd = off;
    size_t perCH = (size_t)N * 4 * 4 + (size_t)N * HID * 4 + (size_t)N * IN_DIM * 4 + 4096;
    int CH = 8;
    while (CH > 1 && fixedEnd + (size_t)CH * perCH > ws_size) CH >>= 1;

    float* m1   = (float*)alloc((size_t)CH * N * 4);
    float* l1   = (float*)alloc((size_t)CH * N * 4);
    float* m2   = (float*)alloc((size_t)CH * N * 4);
    float* l2   = (float*)alloc((size_t)CH * N * 4);
    float* acc1 = (float*)alloc((size_t)CH * N * HID * 4);
    float* acc2 = (float*)alloc((size_t)CH * N * IN_DIM * 4);
    if (off > ws_size && CH == 1) acc2 = out;  // in-place combine is element-exact

    // ---- pack weights + cast x
    pack_weights<<<dim3((512 * 256 + 255) / 256), dim3(256), 0, stream>>>(
        Wq1, Wk1, Wv1, Ws1, bq1, bk1, bv1, bs1, WT1, B1, 256, 128);
    pack_weights<<<dim3((1024 * 128 + 255) / 256), dim3(256), 0, stream>>>(
        Wq4, Wk4, Wv4, Ws4, bq4, bk4, bv4, bs4, WT4, B4, 128, 256);
    cast_x<<<dim3((N * IN_DIM + 255) / 256), dim3(256), 0, stream>>>(x, xb, N * IN_DIM);

    // ---- layer 1
    proj_gemm<256><<<dim3((N / 16) * (512 / 64) / 4), dim3(256), 0, stream>>>(
        xb, WT1, B1, q1, k1, v1, skip1, 512);
    attn_partial<128, 64><<<dim3(N / 64, CH), dim3(256), 0, stream>>>(
        q1, k1, v1, acc1, m1, l1, N / CH, 0.088388347648318447f);
    combine_kernel<128, true><<<dim3(N), dim3(128), 0, stream>>>(
        acc1, m1, l1, skip1, (float*)nullptr, h1, CH);

    // ---- layer 2
    proj_gemm<128><<<dim3((N / 16) * (1024 / 64) / 4), dim3(256), 0, stream>>>(
        h1, WT4, B4, q4, k4, v4, skip4, 1024);
    attn_partial<256, 32><<<dim3(N / 64, CH), dim3(256), 0, stream>>>(
        q4, k4, v4, acc2, m2, l2, N / CH, 0.0625f);
    combine_kernel<256, false><<<dim3(N), dim3(256), 0, stream>>>(
        acc2, m2, l2, skip4, out, (unsigned short*)nullptr, CH);
}

// Round 2
// 391.736 us; speedup vs baseline: 2.2605x; 2.2605x over previous
//
#include <hip/hip_runtime.h>

#define N_ROWS 8192
#define IN_DIM 256
#define HID 128

typedef __attribute__((ext_vector_type(8))) short bf16x8;
typedef __attribute__((ext_vector_type(4))) float f32x4;

__device__ __forceinline__ unsigned short f2bf(float f) {
    union { float f; unsigned u; } v; v.f = f;
    unsigned r = (v.u + 0x7FFFu + ((v.u >> 16) & 1u)) >> 16;
    return (unsigned short)r;
}

// ---------------- pack: 4 weights [K][HO] -> WT bf16 [4*HO][K], biases -> B [4*HO]
__global__ void pack_weights(const float* __restrict__ W0, const float* __restrict__ W1,
                             const float* __restrict__ W2, const float* __restrict__ W3,
                             const float* __restrict__ b0, const float* __restrict__ b1,
                             const float* __restrict__ b2, const float* __restrict__ b3,
                             unsigned short* __restrict__ WT, float* __restrict__ B,
                             int K, int HO)
{
    int NT = 4 * HO;
    int idx = blockIdx.x * blockDim.x + threadIdx.x;
    if (idx < NT * K) {
        int n = idx / K, k = idx - n * K;
        int s = n / HO, sn = n - s * HO;
        const float* W = (s == 0) ? W0 : (s == 1) ? W1 : (s == 2) ? W2 : W3;
        WT[idx] = f2bf(W[k * HO + sn]);
    }
    if (idx < NT) {
        int s = idx / HO, sn = idx - s * HO;
        const float* b = (s == 0) ? b0 : (s == 1) ? b1 : (s == 2) ? b2 : b3;
        B[idx] = b[sn];
    }
}

__global__ void cast_x(const float* __restrict__ in, unsigned short* __restrict__ out, int n) {
    int i = blockIdx.x * blockDim.x + threadIdx.x;
    if (i < n) out[i] = f2bf(in[i]);
}

// ---------------- tiled bf16 transpose: in [R][C] -> out [C][R]
__global__ void transpose_bf16(const unsigned short* __restrict__ in,
                               unsigned short* __restrict__ out, int R, int C)
{
    __shared__ unsigned short t[32][33];
    const int tx = threadIdx.x, ty = threadIdx.y;
    const int r0 = blockIdx.y * 32, c0 = blockIdx.x * 32;
    #pragma unroll
    for (int j = 0; j < 32; j += 8)
        t[ty + j][tx] = in[(size_t)(r0 + ty + j) * C + c0 + tx];
    __syncthreads();
    #pragma unroll
    for (int j = 0; j < 32; j += 8)
        out[(size_t)(c0 + ty + j) * R + r0 + tx] = t[tx][ty + j];
}

// ---------------- fused projection GEMM: A[M][K] bf16 x WT[NT][K] -> q,k,v bf16 + skip f32
template<int K>
__global__ __launch_bounds__(256) void proj_gemm(
    const unsigned short* __restrict__ A, const unsigned short* __restrict__ WT,
    const float* __restrict__ bias,
    unsigned short* __restrict__ qo, unsigned short* __restrict__ ko,
    unsigned short* __restrict__ vo, float* __restrict__ skip,
    int NT)
{
    const int lane = threadIdx.x & 63;
    const int wid = (blockIdx.x * blockDim.x + threadIdx.x) >> 6;
    const int nStrips = NT / 64;
    const int mTile = wid / nStrips;
    const int nBase = (wid - mTile * nStrips) * 64;
    const int l15 = lane & 15, lg = lane >> 4;
    const int HO = NT >> 2;

    f32x4 acc[4];
    #pragma unroll
    for (int c = 0; c < 4; ++c) acc[c] = f32x4{0.f, 0.f, 0.f, 0.f};

    const unsigned short* Ap = A + (size_t)(mTile * 16 + l15) * K + lg * 8;
    #pragma unroll
    for (int t = 0; t < K / 32; ++t) {
        bf16x8 a = *(const bf16x8*)(Ap + t * 32);
        #pragma unroll
        for (int c = 0; c < 4; ++c) {
            bf16x8 b = *(const bf16x8*)(WT + (size_t)(nBase + c * 16 + l15) * K + t * 32 + lg * 8);
            acc[c] = __builtin_amdgcn_mfma_f32_16x16x32_bf16(a, b, acc[c], 0, 0, 0);
        }
    }
    #pragma unroll
    for (int c = 0; c < 4; ++c) {
        int col = nBase + c * 16 + l15;
        int sec = col / HO, sc = col - sec * HO;
        float bv = bias[col];
        #pragma unroll
        for (int r = 0; r < 4; ++r) {
            int mrow = mTile * 16 + lg * 4 + r;
            float val = acc[c][r] + bv;
            size_t o = (size_t)mrow * HO + sc;
            if (sec == 0) qo[o] = f2bf(val);
            else if (sec == 1) ko[o] = f2bf(val);
            else if (sec == 2) vo[o] = f2bf(val);
            else skip[o] = val;
        }
    }
}

// ---------------- flash-attention partial over a K-chunk.
// W waves (W*64 threads), QW q-rows per wave. K staged row-major (pad);
// V consumed from pre-transposed VT_global [D][N] -> coalesced row staging.
template<int D, int KB, int W, int QW>
__global__ __launch_bounds__(W * 64) void attn_partial(
    const unsigned short* __restrict__ Qm,
    const unsigned short* __restrict__ Km,
    const unsigned short* __restrict__ VTg,
    float* __restrict__ accOut, float* __restrict__ mOut, float* __restrict__ lOut,
    int chunkLen, float scale)
{
    constexpr int LK = D + 8;
    constexpr int LV = KB + 8;
    constexpr int LP = KB + 8;
    constexpr int MT = QW / 16;
    __shared__ __align__(16) unsigned short Kl[KB * LK];
    __shared__ __align__(16) unsigned short VTl[D * LV];
    __shared__ __align__(16) unsigned short Pl[W * QW * LP];

    const int lane = threadIdx.x & 63;
    const int w = threadIdx.x >> 6;
    const int l15 = lane & 15, lg = lane >> 4;
    const int qrow = blockIdx.x * (W * QW) + w * QW;
    const int ch = blockIdx.y;
    const int kStart = ch * chunkLen;
    const size_t NN = N_ROWS;

    bf16x8 qf[MT][D / 32];
    #pragma unroll
    for (int m = 0; m < MT; ++m)
        #pragma unroll
        for (int t = 0; t < D / 32; ++t)
            qf[m][t] = *(const bf16x8*)(Qm + (size_t)(qrow + m * 16 + l15) * D + t * 32 + lg * 8);

    f32x4 acc[MT][D / 16];
    float mRow[MT][4], lRow[MT][4];
    #pragma unroll
    for (int m = 0; m < MT; ++m) {
        #pragma unroll
        for (int dt = 0; dt < D / 16; ++dt) acc[m][dt] = f32x4{0.f, 0.f, 0.f, 0.f};
        #pragma unroll
        for (int r = 0; r < 4; ++r) { mRow[m][r] = -__builtin_inff(); lRow[m][r] = 0.f; }
    }

    for (int kt = 0; kt < chunkLen; kt += KB) {
        __syncthreads();
        const int kGlob = kStart + kt;
        // stage K rows (coalesced int4)
        for (int c = threadIdx.x; c < KB * D / 8; c += W * 64) {
            int r = c / (D / 8), c8 = c - r * (D / 8);
            *(int4*)(&Kl[r * LK + c8 * 8]) =
                *(const int4*)(Km + (size_t)(kGlob + r) * D + c8 * 8);
        }
        // stage VT rows (coalesced int4 from pre-transposed V)
        for (int c = threadIdx.x; c < D * KB / 8; c += W * 64) {
            int r = c / (KB / 8), c8 = c - r * (KB / 8);
            *(int4*)(&VTl[r * LV + c8 * 8]) =
                *(const int4*)(VTg + (size_t)r * NN + kGlob + c8 * 8);
        }
        __syncthreads();

        #pragma unroll
        for (int m = 0; m < MT; ++m) {
            // S = Q @ K^T
            f32x4 s[KB / 16];
            #pragma unroll
            for (int c = 0; c < KB / 16; ++c) {
                s[c] = f32x4{0.f, 0.f, 0.f, 0.f};
                #pragma unroll
                for (int t = 0; t < D / 32; ++t) {
                    bf16x8 b = *(const bf16x8*)(&Kl[(c * 16 + l15) * LK + t * 32 + lg * 8]);
                    s[c] = __builtin_amdgcn_mfma_f32_16x16x32_bf16(qf[m][t], b, s[c], 0, 0, 0);
                }
            }
            float tmax[4];
            #pragma unroll
            for (int r = 0; r < 4; ++r) {
                float v = -__builtin_inff();
                #pragma unroll
                for (int c = 0; c < KB / 16; ++c) { s[c][r] *= scale; v = fmaxf(v, s[c][r]); }
                #pragma unroll
                for (int mk = 1; mk <= 8; mk <<= 1) v = fmaxf(v, __shfl_xor(v, mk));
                tmax[r] = v;
            }
            float alpha[4];
            #pragma unroll
            for (int r = 0; r < 4; ++r) {
                float mNew = fmaxf(mRow[m][r], tmax[r]);
                alpha[r] = __expf(mRow[m][r] - mNew);
                mRow[m][r] = mNew;
            }
            float ls[4] = {0.f, 0.f, 0.f, 0.f};
            #pragma unroll
            for (int c = 0; c < KB / 16; ++c) {
                #pragma unroll
                for (int r = 0; r < 4; ++r) {
                    float p = __expf(s[c][r] - mRow[m][r]);
                    ls[r] += p;
                    Pl[(w * QW + m * 16 + lg * 4 + r) * LP + c * 16 + l15] = f2bf(p);
                }
            }
            #pragma unroll
            for (int r = 0; r < 4; ++r) {
                float v = ls[r];
                #pragma unroll
                for (int mk = 1; mk <= 8; mk <<= 1) v += __shfl_xor(v, mk);
                lRow[m][r] = lRow[m][r] * alpha[r] + v;
            }
            #pragma unroll
            for (int dt = 0; dt < D / 16; ++dt) {
                #pragma unroll
                for (int r = 0; r < 4; ++r) acc[m][dt][r] *= alpha[r];
            }
            // PV: out += P @ V
            #pragma unroll
            for (int dt = 0; dt < D / 16; ++dt) {
                #pragma unroll
                for (int ks = 0; ks < KB / 32; ++ks) {
                    bf16x8 a = *(const bf16x8*)(&Pl[(w * QW + m * 16 + l15) * LP + ks * 32 + lg * 8]);
                    bf16x8 b = *(const bf16x8*)(&VTl[(dt * 16 + l15) * LV + ks * 32 + lg * 8]);
                    acc[m][dt] = __builtin_amdgcn_mfma_f32_16x16x32_bf16(a, b, acc[m][dt], 0, 0, 0);
                }
            }
        }
    }

    #pragma unroll
    for (int m = 0; m < MT; ++m) {
        #pragma unroll
        for (int dt = 0; dt < D / 16; ++dt) {
            #pragma unroll
            for (int r = 0; r < 4; ++r)
                accOut[((size_t)blockIdx.y * NN + qrow + m * 16 + lg * 4 + r) * D + dt * 16 + l15] =
                    acc[m][dt][r];
        }
        if (l15 == 0) {
            #pragma unroll
            for (int r = 0; r < 4; ++r) {
                mOut[blockIdx.y * NN + qrow + m * 16 + lg * 4 + r] = mRow[m][r];
                lOut[blockIdx.y * NN + qrow + m * 16 + lg * 4 + r] = lRow[m][r];
            }
        }
    }
}

// ---------------- combine K-split partials + skip (+ optional ELU -> bf16)
template<int D, bool ELU>
__global__ void combine_kernel(const float* __restrict__ acc, const float* __restrict__ mArr,
                               const float* __restrict__ lArr, const float* __restrict__ skip,
                               float* __restrict__ outF, unsigned short* __restrict__ outB,
                               int CH)
{
    const int row = blockIdx.x;
    const int d = threadIdx.x;
    const size_t NN = N_ROWS;
    float mStar = -__builtin_inff();
    for (int c = 0; c < CH; ++c) mStar = fmaxf(mStar, mArr[c * NN + row]);
    float denom = 0.f, val = 0.f;
    for (int c = 0; c < CH; ++c) {
        float wgt = __expf(mArr[c * NN + row] - mStar);
        denom += wgt * lArr[c * NN + row];
        val += wgt * acc[((size_t)c * NN + row) * D + d];
    }
    float v = val / denom + skip[(size_t)row * D + d];
    if (ELU) {
        v = (v > 0.f) ? v : expm1f(v);
        outB[(size_t)row * D + d] = f2bf(v);
    } else {
        outF[(size_t)row * D + d] = v;
    }
}

extern "C" void kernel_launch(void* const* d_in, const int* in_sizes, int n_in,
                              void* d_out, int out_size, void* d_ws, size_t ws_size,
                              hipStream_t stream)
{
    (void)in_sizes; (void)n_in; (void)out_size;
    const float* x   = (const float*)d_in[0];
    const float* Wq1 = (const float*)d_in[4];
    const float* bq1 = (const float*)d_in[5];
    const float* Wk1 = (const float*)d_in[6];
    const float* bk1 = (const float*)d_in[7];
    const float* Wv1 = (const float*)d_in[8];
    const float* bv1 = (const float*)d_in[9];
    const float* Ws1 = (const float*)d_in[10];
    const float* bs1 = (const float*)d_in[11];
    const float* Wq4 = (const float*)d_in[12];
    const float* bq4 = (const float*)d_in[13];
    const float* Wk4 = (const float*)d_in[14];
    const float* bk4 = (const float*)d_in[15];
    const float* Wv4 = (const float*)d_in[16];
    const float* bv4 = (const float*)d_in[17];
    const float* Ws4 = (const float*)d_in[18];
    const float* bs4 = (const float*)d_in[19];
    float* out = (float*)d_out;

    const int N = N_ROWS;
    size_t off = 0;
    auto alloc = [&](size_t bytes) -> void* {
        void* p = (char*)d_ws + off;
        off = (off + bytes + 255) & ~(size_t)255;
        return p;
    };
    unsigned short* xb  = (unsigned short*)alloc((size_t)N * IN_DIM * 2);
    unsigned short* WT1 = (unsigned short*)alloc((size_t)512 * 256 * 2);
    float* B1           = (float*)alloc(512 * 4);
    unsigned short* WT4 = (unsigned short*)alloc((size_t)1024 * 128 * 2);
    float* B4           = (float*)alloc(1024 * 4);
    unsigned short* q1  = (unsigned short*)alloc((size_t)N * HID * 2);
    unsigned short* k1  = (unsigned short*)alloc((size_t)N * HID * 2);
    unsigned short* v1  = (unsigned short*)alloc((size_t)N * HID * 2);
    unsigned short* VT1g= (unsigned short*)alloc((size_t)HID * N * 2);
    float* skip1        = (float*)alloc((size_t)N * HID * 4);
    unsigned short* h1  = (unsigned short*)alloc((size_t)N * HID * 2);
    unsigned short* q4  = (unsigned short*)alloc((size_t)N * IN_DIM * 2);
    unsigned short* k4  = (unsigned short*)alloc((size_t)N * IN_DIM * 2);
    unsigned short* v4  = (unsigned short*)alloc((size_t)N * IN_DIM * 2);
    unsigned short* VT4g= (unsigned short*)alloc((size_t)IN_DIM * N * 2);
    float* skip4        = (float*)alloc((size_t)N * IN_DIM * 4);

    size_t fixedEnd = off;
    size_t perCH = (size_t)N * 4 * 4 + (size_t)N * HID * 4 + (size_t)N * IN_DIM * 4 + 4096;
    int CH = 8;
    while (CH > 1 && fixedEnd + (size_t)CH * perCH > ws_size) CH >>= 1;

    float* m1   = (float*)alloc((size_t)CH * N * 4);
    float* l1   = (float*)alloc((size_t)CH * N * 4);
    float* m2   = (float*)alloc((size_t)CH * N * 4);
    float* l2   = (float*)alloc((size_t)CH * N * 4);
    float* acc1 = (float*)alloc((size_t)CH * N * HID * 4);
    float* acc2 = (float*)alloc((size_t)CH * N * IN_DIM * 4);
    if (off > ws_size && CH == 1) acc2 = out;  // in-place combine is element-exact

    // ---- pack weights + cast x
    pack_weights<<<dim3((512 * 256 + 255) / 256), dim3(256), 0, stream>>>(
        Wq1, Wk1, Wv1, Ws1, bq1, bk1, bv1, bs1, WT1, B1, 256, 128);
    pack_weights<<<dim3((1024 * 128 + 255) / 256), dim3(256), 0, stream>>>(
        Wq4, Wk4, Wv4, Ws4, bq4, bk4, bv4, bs4, WT4, B4, 128, 256);
    cast_x<<<dim3((N * IN_DIM + 255) / 256), dim3(256), 0, stream>>>(x, xb, N * IN_DIM);

    // ---- layer 1
    proj_gemm<256><<<dim3((N / 16) * (512 / 64) / 4), dim3(256), 0, stream>>>(
        xb, WT1, B1, q1, k1, v1, skip1, 512);
    transpose_bf16<<<dim3(HID / 32, N / 32), dim3(32, 8), 0, stream>>>(v1, VT1g, N, HID);
    attn_partial<128, 64, 8, 16><<<dim3(N / 128, CH), dim3(512), 0, stream>>>(
        q1, k1, VT1g, acc1, m1, l1, N / CH, 0.088388347648318447f);
    combine_kernel<128, true><<<dim3(N), dim3(128), 0, stream>>>(
        acc1, m1, l1, skip1, (float*)nullptr, h1, CH);

    // ---- layer 2
    proj_gemm<128><<<dim3((N / 16) * (1024 / 64) / 4), dim3(256), 0, stream>>>(
        h1, WT4, B4, q4, k4, v4, skip4, 1024);
    transpose_bf16<<<dim3(IN_DIM / 32, N / 32), dim3(32, 8), 0, stream>>>(v4, VT4g, N, IN_DIM);
    attn_partial<256, 32, 8, 16><<<dim3(N / 128, CH), dim3(512), 0, stream>>>(
        q4, k4, VT4g, acc2, m2, l2, N / CH, 0.0625f);
    combine_kernel<256, false><<<dim3(N), dim3(256), 0, stream>>>(
        acc2, m2, l2, skip4, out, (unsigned short*)nullptr, CH);
}